// Round 5
// baseline (9510.387 us; speedup 1.0000x reference)
//
#include <hip/hip_runtime.h>
#include <hip/hip_bf16.h>

typedef __hip_bfloat16 bf16;

#define E_DIM 1024
#define H_DIM 16
#define N_DIM 4096
#define B_DIM 4
#define D_DIM 64
#define G_WIN 32   // N / 128
#define NC 32      // N / 128
#define M_ROWS 16384  // N*B

// ---------------- Projection GEMM: val[m,e] = sum_k X[m,k]*W[e,k] + bias[e]
// X, W, bias fp32. Scatter bf16 to [B,H,N,D] with scale. m = n*B+b, e = h*64+d.
__global__ __launch_bounds__(256) void gemm_proj(
    const float* __restrict__ X, const float* __restrict__ W,
    const float* __restrict__ bias, float scale, bf16* __restrict__ out)
{
    __shared__ float Xs[32][33];
    __shared__ float Ws[32][33];
    int tx = threadIdx.x;        // 0..31
    int ty = threadIdx.y;        // 0..7
    int row0 = blockIdx.y * 32;
    int col0 = blockIdx.x * 32;
    float acc[4] = {0.f, 0.f, 0.f, 0.f};

    for (int k0 = 0; k0 < E_DIM; k0 += 32) {
#pragma unroll
        for (int i = 0; i < 4; i++) {
            int r = ty + i * 8;
            Xs[r][tx] = X[(size_t)(row0 + r) * E_DIM + k0 + tx];
            Ws[r][tx] = W[(size_t)(col0 + r) * E_DIM + k0 + tx];
        }
        __syncthreads();
#pragma unroll
        for (int kk = 0; kk < 32; kk++) {
            float wv = Ws[tx][kk];
#pragma unroll
            for (int i = 0; i < 4; i++)
                acc[i] += Xs[ty + i * 8][kk] * wv;
        }
        __syncthreads();
    }

#pragma unroll
    for (int i = 0; i < 4; i++) {
        int m = row0 + ty + i * 8;
        int e = col0 + tx;
        float val = (acc[i] + bias[e]) * scale;
        int n = m >> 2, b = m & 3;
        int h = e >> 6, d = e & 63;
        out[((((size_t)b * H_DIM + h) * N_DIM + n) * D_DIM) + d] = (bf16)val;
    }
}

// ---------------- Final GEMM: X gathered from [B,H,N,D] bf16; W,bias fp32; out fp32 [N,B,E]
__global__ __launch_bounds__(256) void gemm_final(
    const bf16* __restrict__ Xbhnd, const float* __restrict__ W,
    const float* __restrict__ bias, float* __restrict__ out)
{
    __shared__ float Xs[32][33];
    __shared__ float Ws[32][33];
    int tx = threadIdx.x;
    int ty = threadIdx.y;
    int row0 = blockIdx.y * 32;
    int col0 = blockIdx.x * 32;
    float acc[4] = {0.f, 0.f, 0.f, 0.f};

    for (int k0 = 0; k0 < E_DIM; k0 += 32) {
#pragma unroll
        for (int i = 0; i < 4; i++) {
            int r = ty + i * 8;
            int m = row0 + r;
            int k = k0 + tx;
            // X[m][k] with m=n*B+b, k=h*64+d, stored [B,H,N,D]
            int n = m >> 2, b = m & 3;
            int h = k >> 6, d = k & 63;
            Xs[r][tx] = (float)Xbhnd[((((size_t)b * H_DIM + h) * N_DIM + n) * D_DIM) + d];
            Ws[r][tx] = W[(size_t)(col0 + r) * E_DIM + k0 + tx];
        }
        __syncthreads();
#pragma unroll
        for (int kk = 0; kk < 32; kk++) {
            float wv = Ws[tx][kk];
#pragma unroll
            for (int i = 0; i < 4; i++)
                acc[i] += Xs[ty + i * 8][kk] * wv;
        }
        __syncthreads();
    }

#pragma unroll
    for (int i = 0; i < 4; i++) {
        int m = row0 + ty + i * 8;
        int e = col0 + tx;
        out[(size_t)m * E_DIM + e] = acc[i] + bias[e];
    }
}

// ---------------- Chunk stats: rf_k_bar, rfa_chunk per (b,h,c) ----------------
__global__ __launch_bounds__(128) void chunk_stats(
    const bf16* __restrict__ q_s, const bf16* __restrict__ kbuf, const bf16* __restrict__ vbuf,
    const float* __restrict__ mqw, const float* __restrict__ mqb,
    const float* __restrict__ mqg, const float* __restrict__ mqbe,
    const float* __restrict__ mkw, const float* __restrict__ mkb,
    const float* __restrict__ mkg, const float* __restrict__ mkbe,
    float* __restrict__ rf_k_bar, float* __restrict__ rfa_chunk)
{
    int bid = blockIdx.x;
    int c = bid % NC;
    int bh = bid / NC;           // b*H + h
    int tid = threadIdx.x;

    __shared__ float qm[64], km[64], qb_s[64], kb_s[64], mu_s[64], sc[128];
    __shared__ float stats[4];

    size_t base = ((size_t)bh * N_DIM + c * 128) * D_DIM;

    // chunk means (q already scaled by 0.125, matching reference rf_q)
    if (tid < 64) {
        float s = 0.f;
        for (int p = 0; p < 128; p++) s += (float)q_s[base + p * 64 + tid];
        qm[tid] = s * (1.0f / 128.0f);
    } else {
        int d = tid - 64;
        float s = 0.f;
        for (int p = 0; p < 128; p++) s += (float)kbuf[base + p * 64 + d];
        km[d] = s * (1.0f / 128.0f);
    }
    __syncthreads();

    // D x D linear
    if (tid < 64) {
        float t = mqb[tid];
        for (int d2 = 0; d2 < 64; d2++) t += qm[d2] * mqw[tid * 64 + d2];
        qb_s[tid] = t;
    } else {
        int d = tid - 64;
        float t = mkb[d];
        for (int d2 = 0; d2 < 64; d2++) t += km[d2] * mkw[d * 64 + d2];
        kb_s[d] = t;
    }
    __syncthreads();

    // layernorm stats
    if (tid == 0) {
        float m = 0.f;
        for (int d = 0; d < 64; d++) m += qb_s[d];
        m *= (1.0f / 64.0f);
        float vv = 0.f;
        for (int d = 0; d < 64; d++) { float x = qb_s[d] - m; vv += x * x; }
        vv *= (1.0f / 64.0f);
        stats[0] = m; stats[1] = rsqrtf(vv + 1e-5f);
    } else if (tid == 64) {
        float m = 0.f;
        for (int d = 0; d < 64; d++) m += kb_s[d];
        m *= (1.0f / 64.0f);
        float vv = 0.f;
        for (int d = 0; d < 64; d++) { float x = kb_s[d] - m; vv += x * x; }
        vv *= (1.0f / 64.0f);
        stats[2] = m; stats[3] = rsqrtf(vv + 1e-5f);
    }
    __syncthreads();

    if (tid < 64) {
        float qn = (qb_s[tid] - stats[0]) * stats[1] * mqg[tid] + mqbe[tid];
        float kn = (kb_s[tid] - stats[2]) * stats[3] * mkg[tid] + mkbe[tid];
        mu_s[tid] = qn + kn;
        rf_k_bar[(size_t)bh * NC * 64 + c * 64 + tid] = kn;
    }
    __syncthreads();

    // log_proj_k per key row p
    {
        float dot = 0.f, ss = 0.f;
        const bf16* kr = kbuf + base + tid * 64;
        for (int d = 0; d < 64; d++) {
            float kv = (float)kr[d];
            dot += mu_s[d] * kv;
            ss += kv * kv;
        }
        sc[tid] = dot * 0.125f - 0.125f * 0.5f * ss;
    }
    __syncthreads();
    if (tid == 0) {
        float m = sc[0];
        for (int p = 1; p < 128; p++) m = fmaxf(m, sc[p]);
        stats[0] = m;
    }
    __syncthreads();
    float e = expf(sc[tid] - stats[0]);
    sc[tid] = e;
    __syncthreads();
    if (tid == 0) {
        float s = 0.f;
        for (int p = 0; p < 128; p++) s += sc[p];
        stats[1] = 1.0f / s;
    }
    __syncthreads();
    sc[tid] *= stats[1];
    __syncthreads();

    // rfa_chunk[d] = sum_p beta[p] * v[p][d]
    if (tid < 64) {
        float acc = 0.f;
        for (int p = 0; p < 128; p++) acc += sc[p] * (float)vbuf[base + p * 64 + tid];
        rfa_chunk[(size_t)bh * NC * 64 + c * 64 + tid] = acc;
    }
}

// ---------------- Windowed attention per (b,h,g): q bf16 in, attn bf16 out ([B,H,N,D]) ----
__global__ __launch_bounds__(256) void attn_kernel(
    const bf16* __restrict__ qin, const bf16* __restrict__ kbuf, const bf16* __restrict__ vbuf,
    const float* __restrict__ rf_k_bar, const float* __restrict__ rfa_chunk,
    bf16* __restrict__ aout)
{
    int bid = blockIdx.x;
    int g = bid % G_WIN;
    int bh = bid / G_WIN;  // b*H + h
    int tid = threadIdx.x;

    __shared__ float qt[32][64];
    __shared__ float S[32][288];

    size_t kvbase = (size_t)bh * N_DIM * D_DIM;
    const float* kb_ = rf_k_bar + (size_t)bh * NC * 64;
    const float* rc_ = rfa_chunk + (size_t)bh * NC * 64;

    for (int it = 0; it < 4; it++) {
        int i0 = it * 32;
        // load q tile (32 rows x 64)
        for (int idx = tid; idx < 32 * 64; idx += 256) {
            int r = idx >> 6, d = idx & 63;
            qt[r][d] = (float)qin[kvbase + (size_t)(g * 128 + i0 + r) * 64 + d];
        }
        __syncthreads();

        // scores: 32 rows x 288 cols
        for (int idx = tid; idx < 32 * 288; idx += 256) {
            int r = idx / 288, j = idx % 288;
            int i = i0 + r;
            float sc;
            if (j < 256) {
                int kidx = g * 128 + j - 128;
                if (j <= i + 128 && kidx >= 0) {
                    const bf16* kr = kbuf + kvbase + (size_t)kidx * 64;
                    float dot = 0.f;
                    for (int d = 0; d < 64; d++) dot += qt[r][d] * (float)kr[d];
                    sc = dot;
                } else sc = -1e9f;
            } else {
                int c = j - 256;
                if (c < g) {
                    const float* kr = kb_ + c * 64;
                    float dot = 0.f;
                    for (int d = 0; d < 64; d++) dot += qt[r][d] * kr[d];
                    sc = dot;
                } else sc = -1e9f;
            }
            S[r][j] = sc;
        }
        __syncthreads();

        // softmax per row (288 entries)
        if (tid < 32) {
            int r = tid;
            float m = -1e30f;
            for (int j = 0; j < 288; j++) m = fmaxf(m, S[r][j]);
            float s = 0.f;
            for (int j = 0; j < 288; j++) { float ev = expf(S[r][j] - m); S[r][j] = ev; s += ev; }
            float inv = 1.0f / s;
            for (int j = 0; j < 288; j++) S[r][j] *= inv;
        }
        __syncthreads();

        // out[r][d] = sum_j P*v + sum_c P*rfa_chunk
        for (int idx = tid; idx < 32 * 64; idx += 256) {
            int r = idx >> 6, d = idx & 63;
            int i = i0 + r;
            float acc = 0.f;
            int jstart = (g == 0) ? 128 : 0;
            for (int j = jstart; j <= i + 128; j++) {
                int kidx = g * 128 + j - 128;
                acc += S[r][j] * (float)vbuf[kvbase + (size_t)kidx * 64 + d];
            }
            for (int c = 0; c < g; c++) acc += S[r][256 + c] * rc_[c * 64 + d];
            aout[kvbase + (size_t)(g * 128 + i0 + r) * 64 + d] = (bf16)acc;
        }
        __syncthreads();
    }
}

extern "C" void kernel_launch(void* const* d_in, const int* in_sizes, int n_in,
                              void* d_out, int out_size, void* d_ws, size_t ws_size,
                              hipStream_t stream) {
    // All inputs fp32 per the reference (jnp.float32 everywhere).
    const float* query = (const float*)d_in[0];
    const float* Wq   = (const float*)d_in[1];
    const float* bq   = (const float*)d_in[2];
    const float* Wk   = (const float*)d_in[3];
    const float* bk   = (const float*)d_in[4];
    const float* Wv   = (const float*)d_in[5];
    const float* bv   = (const float*)d_in[6];
    const float* Wo   = (const float*)d_in[7];
    const float* bo   = (const float*)d_in[8];
    const float* mqw  = (const float*)d_in[9];
    const float* mqb  = (const float*)d_in[10];
    const float* mqg  = (const float*)d_in[11];
    const float* mqbe = (const float*)d_in[12];
    const float* mkw  = (const float*)d_in[13];
    const float* mkb  = (const float*)d_in[14];
    const float* mkg  = (const float*)d_in[15];
    const float* mkbe = (const float*)d_in[16];

    const size_t SZ = (size_t)B_DIM * H_DIM * N_DIM * D_DIM; // 16,777,216 elems
    const size_t STATS = (size_t)B_DIM * H_DIM * NC * D_DIM; // 131,072 elems

    // ws layout (65 MiB, proven to fit in round 4): k,v bf16 + fp32 stats
    bf16* kb = (bf16*)d_ws;
    bf16* vb = kb + SZ;
    float* rf_k_bar  = (float*)(vb + SZ);
    float* rfa_chunk = rf_k_bar + STATS;

    // d_out (64 MiB fp32): 1st half holds q bf16 [B,H,N,D], 2nd half attn-out bf16.
    float* outf = (float*)d_out;
    bf16* qb = (bf16*)d_out;       // SZ bf16 = 32 MiB
    bf16* ab = qb + SZ;            // SZ bf16 = 32 MiB

    dim3 blk(32, 8);
    dim3 grd(E_DIM / 32, M_ROWS / 32);

    gemm_proj<<<grd, blk, 0, stream>>>(query, Wq, bq, 0.125f, qb);
    gemm_proj<<<grd, blk, 0, stream>>>(query, Wk, bk, 1.0f, kb);
    gemm_proj<<<grd, blk, 0, stream>>>(query, Wv, bv, 1.0f, vb);

    chunk_stats<<<B_DIM * H_DIM * NC, 128, 0, stream>>>(
        qb, kb, vb, mqw, mqb, mqg, mqbe, mkw, mkb, mkg, mkbe, rf_k_bar, rfa_chunk);

    attn_kernel<<<B_DIM * H_DIM * G_WIN, 256, 0, stream>>>(
        qb, kb, vb, rf_k_bar, rfa_chunk, ab);

    // k region is dead; stage attn output there so the final GEMM doesn't read d_out
    hipMemcpyAsync(kb, ab, SZ * sizeof(bf16), hipMemcpyDeviceToDevice, stream);

    gemm_final<<<grd, blk, 0, stream>>>(kb, Wo, bo, outf);
}

// Round 8
// 4372.895 us; speedup vs baseline: 2.1748x; 2.1748x over previous
//
#include <hip/hip_runtime.h>
#include <hip/hip_bf16.h>

typedef __hip_bfloat16 bf16;
typedef __attribute__((ext_vector_type(8))) short bf16x8;
typedef __attribute__((ext_vector_type(4))) float f32x4;

#define E_DIM 1024
#define H_DIM 16
#define N_DIM 4096
#define B_DIM 4
#define D_DIM 64
#define G_WIN 32   // N / 128
#define NC 32      // N / 128
#define M_ROWS 16384  // N*B

// ---------------- fp32 -> bf16 bulk convert (8 elems/thread) ----------------
__global__ __launch_bounds__(256) void cvt_f32_bf16(
    const float* __restrict__ in, bf16* __restrict__ out)
{
    int i = (blockIdx.x * 256 + threadIdx.x) * 8;
    float4 f0 = *(const float4*)(in + i);
    float4 f1 = *(const float4*)(in + i + 4);
    union { bf16 t[8]; uint4 u; } pk;
    pk.t[0] = (bf16)f0.x; pk.t[1] = (bf16)f0.y; pk.t[2] = (bf16)f0.z; pk.t[3] = (bf16)f0.w;
    pk.t[4] = (bf16)f1.x; pk.t[5] = (bf16)f1.y; pk.t[6] = (bf16)f1.z; pk.t[7] = (bf16)f1.w;
    *(uint4*)(out + i) = pk.u;
}

// ---------------- MFMA GEMM ----------------
// out[m,e] = sum_k A[m,k] * W[e,k]  (A bf16 row-major [M][K], W fp32 row-major [e][k])
// 128x128 tile, 4 waves of 64x64, mfma_f32_16x16x32_bf16, BK=32.
// MODE 0: (val + bias)*scale -> bf16 scatter [B,H,N,D]   (m=n*B+b, e=h*64+d)
// MODE 1: val + bias -> fp32 row-major [M][E]
template<int MODE>
__global__ __launch_bounds__(256) void gemm_mfma(
    const bf16* __restrict__ A, const float* __restrict__ W,
    const float* __restrict__ bias, float scale,
    bf16* __restrict__ out_bf, float* __restrict__ out_f)
{
    __shared__ bf16 As[128 * 32];
    __shared__ bf16 Bs[128 * 32];
    int tid  = threadIdx.x;
    int lane = tid & 63;
    int wv   = tid >> 6;
    int wm   = (wv >> 1) * 64;
    int wn   = (wv & 1) * 64;
    int quad = lane >> 4;
    int l16  = lane & 15;
    int row0 = blockIdx.y * 128;
    int col0 = blockIdx.x * 128;
    f32x4 acc[4][4] = {};

    for (int k0 = 0; k0 < E_DIM; k0 += 32) {
        // A tile: 128 rows x 32 cols bf16 via global_load_lds (16B per lane)
#pragma unroll
        for (int i = 0; i < 2; i++) {
            int idx = tid + i * 256;
            int r = idx >> 2, c = idx & 3;
            const bf16* g = A + (size_t)(row0 + r) * E_DIM + k0 + c * 8;
            __builtin_amdgcn_global_load_lds(
                (const __attribute__((address_space(1))) void*)g,
                (__attribute__((address_space(3))) void*)(As + idx * 8), 16, 0, 0);
        }
        // W tile: fp32 -> bf16 on the fly
#pragma unroll
        for (int i = 0; i < 2; i++) {
            int idx = tid + i * 256;
            int e = idx >> 2, c = idx & 3;
            const float* wr = W + (size_t)(col0 + e) * E_DIM + k0 + c * 8;
            float4 f0 = *(const float4*)wr;
            float4 f1 = *(const float4*)(wr + 4);
            union { bf16 t[8]; uint4 u; } pk;
            pk.t[0] = (bf16)f0.x; pk.t[1] = (bf16)f0.y;
            pk.t[2] = (bf16)f0.z; pk.t[3] = (bf16)f0.w;
            pk.t[4] = (bf16)f1.x; pk.t[5] = (bf16)f1.y;
            pk.t[6] = (bf16)f1.z; pk.t[7] = (bf16)f1.w;
            *(uint4*)(Bs + idx * 8) = pk.u;
        }
        __syncthreads();

        bf16x8 af[4], bfr[4];
#pragma unroll
        for (int t = 0; t < 4; t++) {
            af[t]  = *(const bf16x8*)(As + (wm + t * 16 + l16) * 32 + quad * 8);
            bfr[t] = *(const bf16x8*)(Bs + (wn + t * 16 + l16) * 32 + quad * 8);
        }
#pragma unroll
        for (int mt = 0; mt < 4; mt++)
#pragma unroll
            for (int nt = 0; nt < 4; nt++)
                acc[mt][nt] = __builtin_amdgcn_mfma_f32_16x16x32_bf16(
                    af[mt], bfr[nt], acc[mt][nt], 0, 0, 0);
        __syncthreads();
    }

#pragma unroll
    for (int mt = 0; mt < 4; mt++)
#pragma unroll
        for (int nt = 0; nt < 4; nt++)
#pragma unroll
            for (int rg = 0; rg < 4; rg++) {
                int m = row0 + wm + mt * 16 + quad * 4 + rg;
                int e = col0 + wn + nt * 16 + l16;
                float val = acc[mt][nt][rg];
                if (MODE == 0) {
                    float v2 = (val + bias[e]) * scale;
                    int n = m >> 2, bb = m & 3;
                    int h = e >> 6, d = e & 63;
                    out_bf[((((size_t)bb * H_DIM + h) * N_DIM + n) * D_DIM) + d] = (bf16)v2;
                } else {
                    out_f[(size_t)m * E_DIM + e] = val + bias[e];
                }
            }
}

// ---------------- Chunk stats: rf_k_bar, rfa_chunk per (b,h,c) ----------------
__global__ __launch_bounds__(128) void chunk_stats(
    const bf16* __restrict__ q_s, const bf16* __restrict__ kbuf, const bf16* __restrict__ vbuf,
    const float* __restrict__ mqw, const float* __restrict__ mqb,
    const float* __restrict__ mqg, const float* __restrict__ mqbe,
    const float* __restrict__ mkw, const float* __restrict__ mkb,
    const float* __restrict__ mkg, const float* __restrict__ mkbe,
    float* __restrict__ rf_k_bar, float* __restrict__ rfa_chunk)
{
    int bid = blockIdx.x;
    int c = bid % NC;
    int bh = bid / NC;           // b*H + h
    int tid = threadIdx.x;

    __shared__ float qm[64], km[64], qb_s[64], kb_s[64], mu_s[64], sc[128];
    __shared__ float stats[4];

    size_t base = ((size_t)bh * N_DIM + c * 128) * D_DIM;

    if (tid < 64) {
        float s = 0.f;
        for (int p = 0; p < 128; p++) s += (float)q_s[base + p * 64 + tid];
        qm[tid] = s * (1.0f / 128.0f);
    } else {
        int d = tid - 64;
        float s = 0.f;
        for (int p = 0; p < 128; p++) s += (float)kbuf[base + p * 64 + d];
        km[d] = s * (1.0f / 128.0f);
    }
    __syncthreads();

    if (tid < 64) {
        float t = mqb[tid];
        for (int d2 = 0; d2 < 64; d2++) t += qm[d2] * mqw[tid * 64 + d2];
        qb_s[tid] = t;
    } else {
        int d = tid - 64;
        float t = mkb[d];
        for (int d2 = 0; d2 < 64; d2++) t += km[d2] * mkw[d * 64 + d2];
        kb_s[d] = t;
    }
    __syncthreads();

    if (tid == 0) {
        float m = 0.f;
        for (int d = 0; d < 64; d++) m += qb_s[d];
        m *= (1.0f / 64.0f);
        float vv = 0.f;
        for (int d = 0; d < 64; d++) { float x = qb_s[d] - m; vv += x * x; }
        vv *= (1.0f / 64.0f);
        stats[0] = m; stats[1] = rsqrtf(vv + 1e-5f);
    } else if (tid == 64) {
        float m = 0.f;
        for (int d = 0; d < 64; d++) m += kb_s[d];
        m *= (1.0f / 64.0f);
        float vv = 0.f;
        for (int d = 0; d < 64; d++) { float x = kb_s[d] - m; vv += x * x; }
        vv *= (1.0f / 64.0f);
        stats[2] = m; stats[3] = rsqrtf(vv + 1e-5f);
    }
    __syncthreads();

    if (tid < 64) {
        float qn = (qb_s[tid] - stats[0]) * stats[1] * mqg[tid] + mqbe[tid];
        float kn = (kb_s[tid] - stats[2]) * stats[3] * mkg[tid] + mkbe[tid];
        mu_s[tid] = qn + kn;
        rf_k_bar[(size_t)bh * NC * 64 + c * 64 + tid] = kn;
    }
    __syncthreads();

    {
        float dot = 0.f, ss = 0.f;
        const bf16* kr = kbuf + base + tid * 64;
        for (int d = 0; d < 64; d++) {
            float kv = (float)kr[d];
            dot += mu_s[d] * kv;
            ss += kv * kv;
        }
        sc[tid] = dot * 0.125f - 0.125f * 0.5f * ss;
    }
    __syncthreads();
    if (tid == 0) {
        float m = sc[0];
        for (int p = 1; p < 128; p++) m = fmaxf(m, sc[p]);
        stats[0] = m;
    }
    __syncthreads();
    float e = expf(sc[tid] - stats[0]);
    sc[tid] = e;
    __syncthreads();
    if (tid == 0) {
        float s = 0.f;
        for (int p = 0; p < 128; p++) s += sc[p];
        stats[1] = 1.0f / s;
    }
    __syncthreads();
    sc[tid] *= stats[1];
    __syncthreads();

    if (tid < 64) {
        float acc = 0.f;
        for (int p = 0; p < 128; p++) acc += sc[p] * (float)vbuf[base + p * 64 + tid];
        rfa_chunk[(size_t)bh * NC * 64 + c * 64 + tid] = acc;
    }
}

// ---------------- Windowed attention per (b,h,g): out row-major [N*B][E] bf16 ----
__global__ __launch_bounds__(256) void attn_kernel(
    const bf16* __restrict__ qin, const bf16* __restrict__ kbuf, const bf16* __restrict__ vbuf,
    const float* __restrict__ rf_k_bar, const float* __restrict__ rfa_chunk,
    bf16* __restrict__ aout)
{
    int bid = blockIdx.x;
    int g = bid % G_WIN;
    int bh = bid / G_WIN;  // b*H + h
    int b = bh >> 4, h = bh & 15;
    int tid = threadIdx.x;

    __shared__ float qt[32][64];
    __shared__ float S[32][288];

    size_t kvbase = (size_t)bh * N_DIM * D_DIM;
    const float* kb_ = rf_k_bar + (size_t)bh * NC * 64;
    const float* rc_ = rfa_chunk + (size_t)bh * NC * 64;

    for (int it = 0; it < 4; it++) {
        int i0 = it * 32;
        for (int idx = tid; idx < 32 * 64; idx += 256) {
            int r = idx >> 6, d = idx & 63;
            qt[r][d] = (float)qin[kvbase + (size_t)(g * 128 + i0 + r) * 64 + d];
        }
        __syncthreads();

        for (int idx = tid; idx < 32 * 288; idx += 256) {
            int r = idx / 288, j = idx % 288;
            int i = i0 + r;
            float sc;
            if (j < 256) {
                int kidx = g * 128 + j - 128;
                if (j <= i + 128 && kidx >= 0) {
                    const bf16* kr = kbuf + kvbase + (size_t)kidx * 64;
                    float dot = 0.f;
                    for (int d = 0; d < 64; d++) dot += qt[r][d] * (float)kr[d];
                    sc = dot;
                } else sc = -1e9f;
            } else {
                int c = j - 256;
                if (c < g) {
                    const float* kr = kb_ + c * 64;
                    float dot = 0.f;
                    for (int d = 0; d < 64; d++) dot += qt[r][d] * kr[d];
                    sc = dot;
                } else sc = -1e9f;
            }
            S[r][j] = sc;
        }
        __syncthreads();

        if (tid < 32) {
            int r = tid;
            float m = -1e30f;
            for (int j = 0; j < 288; j++) m = fmaxf(m, S[r][j]);
            float s = 0.f;
            for (int j = 0; j < 288; j++) { float ev = expf(S[r][j] - m); S[r][j] = ev; s += ev; }
            float inv = 1.0f / s;
            for (int j = 0; j < 288; j++) S[r][j] *= inv;
        }
        __syncthreads();

        for (int idx = tid; idx < 32 * 64; idx += 256) {
            int r = idx >> 6, d = idx & 63;
            int i = i0 + r;
            float acc = 0.f;
            int jstart = (g == 0) ? 128 : 0;
            for (int j = jstart; j <= i + 128; j++) {
                int kidx = g * 128 + j - 128;
                acc += S[r][j] * (float)vbuf[kvbase + (size_t)kidx * 64 + d];
            }
            for (int c = 0; c < g; c++) acc += S[r][256 + c] * rc_[c * 64 + d];
            int n = g * 128 + i0 + r;
            // row-major [m = n*B + b][e = h*64 + d] for the final MFMA GEMM
            aout[((size_t)n * B_DIM + b) * E_DIM + h * 64 + d] = (bf16)acc;
        }
        __syncthreads();
    }
}

extern "C" void kernel_launch(void* const* d_in, const int* in_sizes, int n_in,
                              void* d_out, int out_size, void* d_ws, size_t ws_size,
                              hipStream_t stream) {
    const float* query = (const float*)d_in[0];
    const float* Wq   = (const float*)d_in[1];
    const float* bq   = (const float*)d_in[2];
    const float* Wk   = (const float*)d_in[3];
    const float* bk   = (const float*)d_in[4];
    const float* Wv   = (const float*)d_in[5];
    const float* bv   = (const float*)d_in[6];
    const float* Wo   = (const float*)d_in[7];
    const float* bo   = (const float*)d_in[8];
    const float* mqw  = (const float*)d_in[9];
    const float* mqb  = (const float*)d_in[10];
    const float* mqg  = (const float*)d_in[11];
    const float* mqbe = (const float*)d_in[12];
    const float* mkw  = (const float*)d_in[13];
    const float* mkb  = (const float*)d_in[14];
    const float* mkg  = (const float*)d_in[15];
    const float* mkbe = (const float*)d_in[16];

    const size_t SZ = (size_t)B_DIM * H_DIM * N_DIM * D_DIM; // 16,777,216 elems
    const size_t STATS = (size_t)B_DIM * H_DIM * NC * D_DIM; // 131,072 elems

    // ws (65 MiB proven): k,v bf16 + fp32 stats
    bf16* kb = (bf16*)d_ws;
    bf16* vb = kb + SZ;
    float* rf_k_bar  = (float*)(vb + SZ);
    float* rfa_chunk = rf_k_bar + STATS;

    // d_out (64 MiB fp32): half1 = q bf16 [B,H,N,D]; half2 = query_bf16, later attn-out bf16.
    float* outf = (float*)d_out;
    bf16* qb  = (bf16*)d_out;      // 32 MiB
    bf16* qbf = qb + SZ;           // 32 MiB: query in bf16, then attn output

    dim3 gblk(256);
    dim3 ggrd(E_DIM / 128, M_ROWS / 128);   // (8, 128)

    // 1. query fp32 -> bf16
    cvt_f32_bf16<<<(M_ROWS * E_DIM) / (256 * 8), 256, 0, stream>>>(query, qbf);

    // 2. projections (MFMA)
    gemm_mfma<0><<<ggrd, gblk, 0, stream>>>(qbf, Wq, bq, 0.125f, qb, nullptr);
    gemm_mfma<0><<<ggrd, gblk, 0, stream>>>(qbf, Wk, bk, 1.0f, kb, nullptr);
    gemm_mfma<0><<<ggrd, gblk, 0, stream>>>(qbf, Wv, bv, 1.0f, vb, nullptr);

    // 3. chunk stats
    chunk_stats<<<B_DIM * H_DIM * NC, 128, 0, stream>>>(
        qb, kb, vb, mqw, mqb, mqg, mqbe, mkw, mkb, mkg, mkbe, rf_k_bar, rfa_chunk);

    // 4. attention -> qbf region (query_bf dead), row-major [N*B][E] bf16
    attn_kernel<<<B_DIM * H_DIM * G_WIN, 256, 0, stream>>>(
        qb, kb, vb, rf_k_bar, rfa_chunk, qbf);

    // 5. stage attn output into kb (dead) so final GEMM doesn't read d_out
    (void)hipMemcpyAsync(kb, qbf, SZ * sizeof(bf16), hipMemcpyDeviceToDevice, stream);

    // 6. output projection (MFMA), fp32 out over all of d_out
    gemm_mfma<1><<<ggrd, gblk, 0, stream>>>(kb, Wo, bo, 1.0f, nullptr, outf);
}